// Round 4
// baseline (3218.370 us; speedup 1.0000x reference)
//
#include <hip/hip_runtime.h>
#include <stdint.h>

#define B_ 128
#define T_ 1024
#define D_ 256
#define H_ 512
#define C_ 1000
#define GB 8          // batch groups (16 rows each)
#define GH 32         // hidden-column groups (16 units each)
#define ROWS 16       // batch rows per WG
#define UN 16         // hidden units per WG
#define KTOT (H_ + D_)   // 768: fused [h | x] K dimension
#define NCOL 64          // 4 gates * UN
#define LDK (KTOT + 8)   // padded LDS row stride
#define TPAD 32          // tag padding: 32 ints = 128 B = 1 line per tag

typedef __bf16 bf16x8 __attribute__((ext_vector_type(8)));
typedef float f32x4 __attribute__((ext_vector_type(4)));
typedef unsigned int u32x4 __attribute__((ext_vector_type(4)));

__device__ __forceinline__ uint16_t f2bf(float f) {
  uint32_t u = __float_as_uint(f);
  u += 0x7FFFu + ((u >> 16) & 1u);   // RNE
  return (uint16_t)(u >> 16);
}
__device__ __forceinline__ float bf2f(uint16_t b) {
  return __uint_as_float(((uint32_t)b) << 16);
}
__device__ __forceinline__ float sigm(float x) { return 1.0f / (1.0f + __expf(-x)); }
__device__ __forceinline__ float tanhfast(float x) { return 2.0f / (1.0f + __expf(-2.0f * x)) - 1.0f; }

// System-scope (sc0 sc1): coherence point = LLC. Safe for any WG placement.
// "=&v" early-clobber so outputs never alias addresses.
__device__ __forceinline__ void load_h2x32_sys(const uint16_t* pA, const uint16_t* pB,
                                               u32x4& a, u32x4& b, u32x4& c, u32x4& d) {
  asm volatile("global_load_dwordx4 %0, %4, off sc0 sc1\n\t"
               "global_load_dwordx4 %1, %4, off offset:16 sc0 sc1\n\t"
               "global_load_dwordx4 %2, %5, off sc0 sc1\n\t"
               "global_load_dwordx4 %3, %5, off offset:16 sc0 sc1\n\t"
               "s_waitcnt vmcnt(0)"
               : "=&v"(a), "=&v"(b), "=&v"(c), "=&v"(d)
               : "v"(pA), "v"(pB) : "memory");
}
__device__ __forceinline__ void store_h16_sys(uint16_t* p, u32x4 v) {
  asm volatile("global_store_dwordx4 %0, %1, off sc0 sc1"
               :: "v"(p), "v"(v) : "memory");
}

// Persistent scan: 256 WGs (1/CU), 256 threads. WG (bb,cg) owns batch rows
// [bb*16,+16) x hidden units [cg*16,+16) for all 4 gates. All cross-WG comm
// system-scope through LLC (proven at 2966us). R4 = that baseline plus ONE
// safe change (no scope / workspace / s_getreg changes — the XCD-L2 fast
// path experiment killed 3 containers and is abandoned):
//   PER-WAVE handshake: h-staging remapped so wave w stages K-columns
//   [128w,128w+128) (chunks hc=4w..4w+3, producers cg'=8w..8w+7). Each
//   wave polls only its own 8 producer tags and stages immediately,
//   instead of wave0 serially polling all 32 while everyone waits at a
//   barrier. The post-poll __syncthreads() is gone.
// Safety audit of the barrier removal:
//   - backpressure: a WG's publish is behind its pre-GEMM barrier, which
//     all 4 waves reach only after their polls; the union of the 4 waves'
//     producer sets is all 32 -> publish still implies all tags >= t, so
//     the 2-slot ring can never be overwritten early;
//   - hOutL reuse: wave0's publish reads hOutL before it can arrive at
//     the next pre-GEMM barrier; other waves write hOutL only after that
//     barrier + GEMM + post-GEMM barrier;
//   - each wave stages exactly the rows/chunks of the producers it polled.
__global__ __launch_bounds__(256, 1) void lstm_scan(
    const float* __restrict__ x,
    const float* __restrict__ Wgx, const float* __restrict__ Wgh, const float* __restrict__ bg,
    const float* __restrict__ Wix, const float* __restrict__ Wih, const float* __restrict__ bi,
    const float* __restrict__ Wfx, const float* __restrict__ Wfh, const float* __restrict__ bf_,
    const float* __restrict__ Wox, const float* __restrict__ Woh, const float* __restrict__ bo,
    uint16_t* __restrict__ hring,   // [2][GH][B_][16] bf16
    int* __restrict__ tags)         // [GB][GH][TPAD], zeroed before launch
{
  __shared__ __align__(16) uint16_t WtL[NCOL * LDK];  // Bt[n][k] bf16
  __shared__ __align__(16) uint16_t AL[ROWS * LDK];   // A[m][k] bf16: [h | x]
  __shared__ float gbuf[4 * ROWS * UN];               // gate pre-acts
  __shared__ __align__(16) uint16_t hOutL[ROWS * UN]; // this WG's h slice

  const int tid = threadIdx.x;
  const int wg  = blockIdx.x;
  const int bb  = wg & 7;
  const int cg  = wg >> 3;
  const int b0  = bb * ROWS;
  const int u0  = cg * UN;

  const float* Whs[4] = {Wgh, Wih, Wfh, Woh};
  const float* Wxs[4] = {Wgx, Wix, Wfx, Wox};

  // ---- load weight slice into LDS (transposed: Wt[n][k]) ----
  {
    const int n    = tid & 63;
    const int kk   = tid >> 6;        // 0..3
    const int gate = n >> 4;
    const int j    = u0 + (n & 15);
    const float* WhP = Whs[gate];
    const float* WxP = Wxs[gate];
    for (int k4 = 0; k4 < KTOT; k4 += 4) {
      int k = k4 + kk;
      float w = (k < H_) ? WhP[(size_t)k * H_ + j] : WxP[(size_t)(k - H_) * H_ + j];
      WtL[n * LDK + k] = f2bf(w);
    }
  }

  const int sr = tid >> 4;   // x staging row 0..15 (coalesced x loads)
  const int sj = tid & 15;   // x staging chunk 0..15
  const int rr = sr;         // pointwise row
  const int uu = sj;         // pointwise unit
  const int hr = tid & 15;   // h staging row 0..15
  const int hc = tid >> 4;   // h staging chunk: wave w covers hc=4w..4w+3

  // thread-pinned state in registers
  float c_reg = 0.0f;
  const float bgr = bg[u0 + uu];
  const float bir = bi[u0 + uu];
  const float bfr = bf_[u0 + uu];
  const float bor = bo[u0 + uu];

  // zero A h-region for t=0 (h[0]==0; never read from global)
  {
    uint64_t* zp = (uint64_t*)&AL[hr * LDK + hc * 32];
#pragma unroll
    for (int j = 0; j < 8; ++j) zp[j] = 0ull;
  }

  const int lane = tid & 63;
  const int wv   = tid >> 6;          // wave = gate
  const int l15  = lane & 15;
  const int q    = lane >> 4;
  const uint16_t* Abase = &AL[l15 * LDK + q * 8];
  const uint16_t* Bbase = &WtL[(wv * UN + l15) * LDK + q * 8];
  // wave wv's 8 producers: cg' = 8*wv .. 8*wv+7 (chunks hc=4wv..4wv+3)
  const int* tag8 = &tags[(bb * GH + (8 * wv + (lane & 7))) * TPAD];

  // slot stride in shorts for hring[slot][cg][b][16]
  const size_t SLOT = (size_t)GH * B_ * 16;

  // ---- prologue: load x[0] into registers ----
  float4 xr0, xr1, xr2, xr3;
  {
    const float* xsrc = x + ((size_t)(b0 + sr) * T_ + 0) * D_ + sj * 16;
    xr0 = ((const float4*)xsrc)[0];
    xr1 = ((const float4*)xsrc)[1];
    xr2 = ((const float4*)xsrc)[2];
    xr3 = ((const float4*)xsrc)[3];
  }

  __syncthreads();

  for (int t = 0; t < T_; ++t) {
    // ---- convert prefetched x[t] -> LDS ----
    {
      uint4 o0, o1;
      o0.x = f2bf(xr0.x) | ((uint32_t)f2bf(xr0.y) << 16);
      o0.y = f2bf(xr0.z) | ((uint32_t)f2bf(xr0.w) << 16);
      o0.z = f2bf(xr1.x) | ((uint32_t)f2bf(xr1.y) << 16);
      o0.w = f2bf(xr1.z) | ((uint32_t)f2bf(xr1.w) << 16);
      o1.x = f2bf(xr2.x) | ((uint32_t)f2bf(xr2.y) << 16);
      o1.y = f2bf(xr2.z) | ((uint32_t)f2bf(xr2.w) << 16);
      o1.z = f2bf(xr3.x) | ((uint32_t)f2bf(xr3.y) << 16);
      o1.w = f2bf(xr3.z) | ((uint32_t)f2bf(xr3.w) << 16);
      uint4* xdst = (uint4*)&AL[sr * LDK + H_ + sj * 16];
      xdst[0] = o0; xdst[1] = o1;
    }

    // ---- wait for + stage h[t] (per-wave: only this wave's 8 producers;
    //      lanes 8..63 poll duplicates of the same 8 lines) ----
    if (t > 0) {
      while (true) {
        int v = __hip_atomic_load(tag8, __ATOMIC_RELAXED,
                                  __HIP_MEMORY_SCOPE_SYSTEM);
        if (__ballot(v < t) == 0ull) break;
      }
      // thread (hr,hc): units 32hc..32hc+31 of row b0+hr = cg'=2hc, 2hc+1
      const uint16_t* base = hring + (size_t)(t & 1) * SLOT;
      const uint16_t* pA = base + ((size_t)(2 * hc) * B_ + b0 + hr) * 16;
      const uint16_t* pB = base + ((size_t)(2 * hc + 1) * B_ + b0 + hr) * 16;
      u32x4 a, b, c, d;
      load_h2x32_sys(pA, pB, a, b, c, d);
      u32x4* adst = (u32x4*)&AL[hr * LDK + hc * 32];
      adst[0] = a; adst[1] = b; adst[2] = c; adst[3] = d;
    }

    // ---- issue x[t+1] prefetch (no vmcnt drain until publish) ----
    {
      const int tn = (t + 1 < T_) ? t + 1 : t;
      const float* xsrc = x + ((size_t)(b0 + sr) * T_ + tn) * D_ + sj * 16;
      xr0 = ((const float4*)xsrc)[0];
      xr1 = ((const float4*)xsrc)[1];
      xr2 = ((const float4*)xsrc)[2];
      xr3 = ((const float4*)xsrc)[3];
    }
    __syncthreads();

    // ---- GEMM: wave wv -> gate wv pre-acts [16 rows, 16 units] ----
    f32x4 a0 = {0.f, 0.f, 0.f, 0.f};
    f32x4 a1 = {0.f, 0.f, 0.f, 0.f};
    f32x4 a2 = {0.f, 0.f, 0.f, 0.f};
    f32x4 a3 = {0.f, 0.f, 0.f, 0.f};
#pragma unroll
    for (int k0 = 0; k0 < KTOT; k0 += 128) {
      bf16x8 av0 = *(const bf16x8*)(Abase + k0);
      bf16x8 bv0 = *(const bf16x8*)(Bbase + k0);
      bf16x8 av1 = *(const bf16x8*)(Abase + k0 + 32);
      bf16x8 bv1 = *(const bf16x8*)(Bbase + k0 + 32);
      bf16x8 av2 = *(const bf16x8*)(Abase + k0 + 64);
      bf16x8 bv2 = *(const bf16x8*)(Bbase + k0 + 64);
      bf16x8 av3 = *(const bf16x8*)(Abase + k0 + 96);
      bf16x8 bv3 = *(const bf16x8*)(Bbase + k0 + 96);
      a0 = __builtin_amdgcn_mfma_f32_16x16x32_bf16(av0, bv0, a0, 0, 0, 0);
      a1 = __builtin_amdgcn_mfma_f32_16x16x32_bf16(av1, bv1, a1, 0, 0, 0);
      a2 = __builtin_amdgcn_mfma_f32_16x16x32_bf16(av2, bv2, a2, 0, 0, 0);
      a3 = __builtin_amdgcn_mfma_f32_16x16x32_bf16(av3, bv3, a3, 0, 0, 0);
    }
    // D layout: row(batch) = q*4+r, col(unit) = lane&15
#pragma unroll
    for (int r = 0; r < 4; ++r) {
      gbuf[wv * (ROWS * UN) + (q * 4 + r) * UN + l15] =
          (a0[r] + a1[r]) + (a2[r] + a3[r]);
    }
    __syncthreads();

    // ---- pointwise update: thread -> (row rr, unit uu) ----
    {
      const int o  = rr * UN + uu;
      float pg = gbuf[0 * (ROWS * UN) + o] + bgr;
      float pi = gbuf[1 * (ROWS * UN) + o] + bir;
      float pf = gbuf[2 * (ROWS * UN) + o] + bfr;
      float po = gbuf[3 * (ROWS * UN) + o] + bor;
      float g  = tanhfast(pg);
      float ii = sigm(pi);
      float ff = sigm(pf);
      float oo = sigm(po);
      float c  = g * ii + c_reg * ff;
      c_reg = c;
      float h = tanhfast(c) * oo;
      hOutL[o] = f2bf(h);
    }
    __syncthreads();

    // ---- publish (wave 0 only): 32 coalesced dwordx4 into this WG's
    //      exclusively-owned 512 B, vmcnt ack, then 1 padded-tag store ----
    if (tid < 32) {
      u32x4 v = *(const u32x4*)&hOutL[tid * 8];
      uint16_t* dst = hring + (size_t)((t + 1) & 1) * SLOT +
                      ((size_t)cg * B_ + b0) * 16 + tid * 8;
      store_h16_sys(dst, v);
      asm volatile("s_waitcnt vmcnt(0)" ::: "memory");
      if (tid == 0) {
        __hip_atomic_store(&tags[(bb * GH + cg) * TPAD], t + 1,
                           __ATOMIC_RELAXED, __HIP_MEMORY_SCOPE_SYSTEM);
      }
    }
    // hOutL reuse ordered by the next pre-GEMM barrier (see audit above)
  }
}

// Final projection: out[b,c] = sum_k h[b,k] * Wph[k,c] + bp[c]
// hfin layout: [GH][B_][16] (slot 0 of hring, since T_ is even)
__global__ __launch_bounds__(256) void lstm_proj(
    const uint16_t* __restrict__ hfin,
    const float* __restrict__ Wph,       // [H_][C_]
    const float* __restrict__ bp,        // [C_]
    float* __restrict__ out)             // [B_][C_]
{
  __shared__ float hL[8 * H_];   // 16 KB
  const int tid = threadIdx.x;
  const int b0  = blockIdx.y * 8;
  const int c   = blockIdx.x * 256 + tid;

  {
    int idx = tid * 16;
#pragma unroll
    for (int e = 0; e < 16; ++e) {
      int i = idx + e;
      int rb = i >> 9, k = i & 511;
      hL[i] = bf2f(hfin[((size_t)(k >> 4) * B_ + b0 + rb) * 16 + (k & 15)]);
    }
  }
  __syncthreads();

  if (c < C_) {
    float acc[8] = {0.f, 0.f, 0.f, 0.f, 0.f, 0.f, 0.f, 0.f};
#pragma unroll 8
    for (int k = 0; k < H_; ++k) {
      float w = Wph[(size_t)k * C_ + c];
#pragma unroll
      for (int rb = 0; rb < 8; ++rb) acc[rb] += hL[rb * H_ + k] * w;
    }
    float bias = bp[c];
#pragma unroll
    for (int rb = 0; rb < 8; ++rb) out[(size_t)(b0 + rb) * C_ + c] = acc[rb] + bias;
  }
}

extern "C" void kernel_launch(void* const* d_in, const int* in_sizes, int n_in,
                              void* d_out, int out_size, void* d_ws, size_t ws_size,
                              hipStream_t stream) {
  const float* x   = (const float*)d_in[0];
  const float* Wgx = (const float*)d_in[1];
  const float* Wgh = (const float*)d_in[2];
  const float* bg  = (const float*)d_in[3];
  const float* Wix = (const float*)d_in[4];
  const float* Wih = (const float*)d_in[5];
  const float* bi  = (const float*)d_in[6];
  const float* Wfx = (const float*)d_in[7];
  const float* Wfh = (const float*)d_in[8];
  const float* bf_ = (const float*)d_in[9];
  const float* Wox = (const float*)d_in[10];
  const float* Woh = (const float*)d_in[11];
  const float* bo  = (const float*)d_in[12];
  const float* Wph = (const float*)d_in[13];
  const float* bp  = (const float*)d_in[14];
  float* out = (float*)d_out;

  // ws: hring [2][GH][B_][16] bf16 (256 KB) | tags [GB][GH][TPAD] (32 KB)
  uint16_t* hring = (uint16_t*)d_ws;
  int* tags = (int*)((char*)d_ws + (size_t)2 * GH * B_ * 16 * sizeof(uint16_t));

  hipMemsetAsync(tags, 0, GB * GH * TPAD * sizeof(int), stream);

  lstm_scan<<<dim3(GB * GH), dim3(256), 0, stream>>>(
      x, Wgx, Wgh, bg, Wix, Wih, bi, Wfx, Wfh, bf_, Wox, Woh, bo, hring, tags);

  // h[T] is in slot T%2 == 0
  const uint16_t* hfin = hring;
  lstm_proj<<<dim3(4, 16), dim3(256), 0, stream>>>(hfin, Wph, bp, out);
}

// Round 5
// 2791.810 us; speedup vs baseline: 1.1528x; 1.1528x over previous
//
#include <hip/hip_runtime.h>
#include <stdint.h>

#define B_ 128
#define T_ 1024
#define D_ 256
#define H_ 512
#define C_ 1000
#define GB 8          // batch groups (16 rows each)
#define GH 32         // hidden-column groups (16 units each)
#define ROWS 16       // batch rows per WG
#define UN 16         // hidden units per WG
#define KTOT (H_ + D_)   // 768: fused [h | x] K dimension
#define NCOL 64          // 4 gates * UN
#define LDK (KTOT + 8)   // padded LDS row stride
#define TPAD 32          // tag padding: 32 ints = 128 B = 1 line per tag

typedef __bf16 bf16x8 __attribute__((ext_vector_type(8)));
typedef float f32x4 __attribute__((ext_vector_type(4)));
typedef unsigned int u32x4 __attribute__((ext_vector_type(4)));

__device__ __forceinline__ uint16_t f2bf(float f) {
  uint32_t u = __float_as_uint(f);
  u += 0x7FFFu + ((u >> 16) & 1u);   // RNE
  return (uint16_t)(u >> 16);
}
__device__ __forceinline__ float bf2f(uint16_t b) {
  return __uint_as_float(((uint32_t)b) << 16);
}
__device__ __forceinline__ float sigm(float x) { return 1.0f / (1.0f + __expf(-x)); }
__device__ __forceinline__ float tanhfast(float x) { return 2.0f / (1.0f + __expf(-2.0f * x)) - 1.0f; }

// System-scope (sc0 sc1): coherence point = LLC. Safe for any WG placement.
// "=&v" early-clobber so outputs never alias addresses.
__device__ __forceinline__ void load_h2x32_sys(const uint16_t* pA, const uint16_t* pB,
                                               u32x4& a, u32x4& b, u32x4& c, u32x4& d) {
  asm volatile("global_load_dwordx4 %0, %4, off sc0 sc1\n\t"
               "global_load_dwordx4 %1, %4, off offset:16 sc0 sc1\n\t"
               "global_load_dwordx4 %2, %5, off sc0 sc1\n\t"
               "global_load_dwordx4 %3, %5, off offset:16 sc0 sc1\n\t"
               "s_waitcnt vmcnt(0)"
               : "=&v"(a), "=&v"(b), "=&v"(c), "=&v"(d)
               : "v"(pA), "v"(pB) : "memory");
}
__device__ __forceinline__ void store_h16_sys(uint16_t* p, u32x4 v) {
  asm volatile("global_store_dwordx4 %0, %1, off sc0 sc1"
               :: "v"(p), "v"(v) : "memory");
}

// Persistent scan: 256 WGs (1/CU), 256 threads. WG (bb,cg) owns batch rows
// [bb*16,+16) x hidden units [cg*16,+16) for all 4 gates. All cross-WG comm
// system-scope through LLC. R5 vs the proven R0 baseline (2966us):
//  - handshake REVERTED to R0 exactly (wave0 polls all 32 tags, then
//    __syncthreads; R4's per-wave polling quadrupled LLC poll traffic and
//    cost 5% — FETCH +12MB proved it);
//  - NEW: the B-operand (weight) MFMA fragments are preloaded ONCE into
//    registers (bf16x8 Bf[6][4] = 96 VGPRs) and the per-step GEMM reads
//    only the A-side from LDS. This halves per-step LDS traffic
//    (192KB -> 96KB, ~-750cy of LDS port time at 128B/clk) and halves
//    bank-conflict stalls (SQ_LDS_BANK_CONFLICT 3.3e8 -> ~1.6e8 expected).
//    We are pinned at 1 WG/CU by LDS, so the extra VGPRs are free
//    (132 -> ~230, still < 256).
__global__ __launch_bounds__(256, 1) void lstm_scan(
    const float* __restrict__ x,
    const float* __restrict__ Wgx, const float* __restrict__ Wgh, const float* __restrict__ bg,
    const float* __restrict__ Wix, const float* __restrict__ Wih, const float* __restrict__ bi,
    const float* __restrict__ Wfx, const float* __restrict__ Wfh, const float* __restrict__ bf_,
    const float* __restrict__ Wox, const float* __restrict__ Woh, const float* __restrict__ bo,
    uint16_t* __restrict__ hring,   // [2][GH][B_][16] bf16
    int* __restrict__ tags)         // [GB][GH][TPAD], zeroed before launch
{
  __shared__ __align__(16) uint16_t WtL[NCOL * LDK];  // Bt[n][k] bf16 (init only)
  __shared__ __align__(16) uint16_t AL[ROWS * LDK];   // A[m][k] bf16: [h | x]
  __shared__ float gbuf[4 * ROWS * UN];               // gate pre-acts
  __shared__ __align__(16) uint16_t hOutL[ROWS * UN]; // this WG's h slice

  const int tid = threadIdx.x;
  const int wg  = blockIdx.x;
  const int bb  = wg & 7;
  const int cg  = wg >> 3;
  const int b0  = bb * ROWS;
  const int u0  = cg * UN;

  const float* Whs[4] = {Wgh, Wih, Wfh, Woh};
  const float* Wxs[4] = {Wgx, Wix, Wfx, Wox};

  // ---- load weight slice into LDS (transposed: Wt[n][k]) ----
  {
    const int n    = tid & 63;
    const int kk   = tid >> 6;        // 0..3
    const int gate = n >> 4;
    const int j    = u0 + (n & 15);
    const float* WhP = Whs[gate];
    const float* WxP = Wxs[gate];
    for (int k4 = 0; k4 < KTOT; k4 += 4) {
      int k = k4 + kk;
      float w = (k < H_) ? WhP[(size_t)k * H_ + j] : WxP[(size_t)(k - H_) * H_ + j];
      WtL[n * LDK + k] = f2bf(w);
    }
  }

  const int sr = tid >> 4;   // staging row 0..15
  const int sj = tid & 15;   // staging chunk 0..15
  const int rr = sr;         // pointwise row
  const int uu = sj;         // pointwise unit

  // thread-pinned state in registers
  float c_reg = 0.0f;
  const float bgr = bg[u0 + uu];
  const float bir = bi[u0 + uu];
  const float bfr = bf_[u0 + uu];
  const float bor = bo[u0 + uu];

  // zero A h-region for t=0 (h[0]==0; never read from global)
  {
    uint64_t* zp = (uint64_t*)&AL[sr * LDK + sj * 32];
#pragma unroll
    for (int j = 0; j < 8; ++j) zp[j] = 0ull;
  }

  const int lane = tid & 63;
  const int wv   = tid >> 6;          // wave = gate
  const int l15  = lane & 15;
  const int q    = lane >> 4;
  const uint16_t* Abase = &AL[l15 * LDK + q * 8];
  const uint16_t* Bbase = &WtL[(wv * UN + l15) * LDK + q * 8];
  const int* myTag = &tags[(bb * GH + (lane & 31)) * TPAD];

  // slot stride in shorts for hring[slot][cg][b][16]
  const size_t SLOT = (size_t)GH * B_ * 16;

  // ---- prologue: load x[0] into registers ----
  float4 xr0, xr1, xr2, xr3;
  {
    const float* xsrc = x + ((size_t)(b0 + sr) * T_ + 0) * D_ + sj * 16;
    xr0 = ((const float4*)xsrc)[0];
    xr1 = ((const float4*)xsrc)[1];
    xr2 = ((const float4*)xsrc)[2];
    xr3 = ((const float4*)xsrc)[3];
  }

  __syncthreads();   // WtL + AL zero complete

  // ---- preload this lane's B fragments into registers (96 VGPRs).
  //      WtL is never read again after this point; per-step GEMM LDS
  //      traffic halves. Fully-unrolled static indexing keeps Bf in
  //      VGPRs (runtime indexing would spill to scratch). ----
  bf16x8 Bf[6][4];
#pragma unroll
  for (int kk = 0; kk < 6; ++kk) {
#pragma unroll
    for (int j = 0; j < 4; ++j) {
      Bf[kk][j] = *(const bf16x8*)(Bbase + kk * 128 + j * 32);
    }
  }

  for (int t = 0; t < T_; ++t) {
    // ---- convert prefetched x[t] -> LDS ----
    {
      uint4 o0, o1;
      o0.x = f2bf(xr0.x) | ((uint32_t)f2bf(xr0.y) << 16);
      o0.y = f2bf(xr0.z) | ((uint32_t)f2bf(xr0.w) << 16);
      o0.z = f2bf(xr1.x) | ((uint32_t)f2bf(xr1.y) << 16);
      o0.w = f2bf(xr1.z) | ((uint32_t)f2bf(xr1.w) << 16);
      o1.x = f2bf(xr2.x) | ((uint32_t)f2bf(xr2.y) << 16);
      o1.y = f2bf(xr2.z) | ((uint32_t)f2bf(xr2.w) << 16);
      o1.z = f2bf(xr3.x) | ((uint32_t)f2bf(xr3.y) << 16);
      o1.w = f2bf(xr3.z) | ((uint32_t)f2bf(xr3.w) << 16);
      uint4* xdst = (uint4*)&AL[sr * LDK + H_ + sj * 16];
      xdst[0] = o0; xdst[1] = o1;
    }

    // ---- wait for + stage h[t] (R0-proven: wave0 polls, all stage) ----
    if (t > 0) {
      if (wv == 0) {
        while (true) {
          int v = __hip_atomic_load(myTag, __ATOMIC_RELAXED,
                                    __HIP_MEMORY_SCOPE_SYSTEM);
          if (__ballot(v < t) == 0ull) break;
        }
      }
      __syncthreads();
      // thread (sr,sj): units 32sj..32sj+31 of row b0+sr = cg'=2sj, 2sj+1
      const uint16_t* base = hring + (size_t)(t & 1) * SLOT;
      const uint16_t* pA = base + ((2 * sj) * B_ + b0 + sr) * 16;
      const uint16_t* pB = base + ((2 * sj + 1) * B_ + b0 + sr) * 16;
      u32x4 a, b, c, d;
      load_h2x32_sys(pA, pB, a, b, c, d);
      u32x4* adst = (u32x4*)&AL[sr * LDK + sj * 32];
      adst[0] = a; adst[1] = b; adst[2] = c; adst[3] = d;
    }

    // ---- issue x[t+1] prefetch (no vmcnt drain until publish) ----
    {
      const int tn = (t + 1 < T_) ? t + 1 : t;
      const float* xsrc = x + ((size_t)(b0 + sr) * T_ + tn) * D_ + sj * 16;
      xr0 = ((const float4*)xsrc)[0];
      xr1 = ((const float4*)xsrc)[1];
      xr2 = ((const float4*)xsrc)[2];
      xr3 = ((const float4*)xsrc)[3];
    }
    __syncthreads();

    // ---- GEMM: wave wv -> gate wv pre-acts [16 rows, 16 units].
    //      A from LDS, B from registers (Bf). ----
    f32x4 a0 = {0.f, 0.f, 0.f, 0.f};
    f32x4 a1 = {0.f, 0.f, 0.f, 0.f};
    f32x4 a2 = {0.f, 0.f, 0.f, 0.f};
    f32x4 a3 = {0.f, 0.f, 0.f, 0.f};
#pragma unroll
    for (int kk = 0; kk < 6; ++kk) {
      const int k0 = kk * 128;
      bf16x8 av0 = *(const bf16x8*)(Abase + k0);
      bf16x8 av1 = *(const bf16x8*)(Abase + k0 + 32);
      bf16x8 av2 = *(const bf16x8*)(Abase + k0 + 64);
      bf16x8 av3 = *(const bf16x8*)(Abase + k0 + 96);
      a0 = __builtin_amdgcn_mfma_f32_16x16x32_bf16(av0, Bf[kk][0], a0, 0, 0, 0);
      a1 = __builtin_amdgcn_mfma_f32_16x16x32_bf16(av1, Bf[kk][1], a1, 0, 0, 0);
      a2 = __builtin_amdgcn_mfma_f32_16x16x32_bf16(av2, Bf[kk][2], a2, 0, 0, 0);
      a3 = __builtin_amdgcn_mfma_f32_16x16x32_bf16(av3, Bf[kk][3], a3, 0, 0, 0);
    }
    // D layout: row(batch) = q*4+r, col(unit) = lane&15
#pragma unroll
    for (int r = 0; r < 4; ++r) {
      gbuf[wv * (ROWS * UN) + (q * 4 + r) * UN + l15] =
          (a0[r] + a1[r]) + (a2[r] + a3[r]);
    }
    __syncthreads();

    // ---- pointwise update: thread -> (row rr, unit uu) ----
    {
      const int o  = rr * UN + uu;
      float pg = gbuf[0 * (ROWS * UN) + o] + bgr;
      float pi = gbuf[1 * (ROWS * UN) + o] + bir;
      float pf = gbuf[2 * (ROWS * UN) + o] + bfr;
      float po = gbuf[3 * (ROWS * UN) + o] + bor;
      float g  = tanhfast(pg);
      float ii = sigm(pi);
      float ff = sigm(pf);
      float oo = sigm(po);
      float c  = g * ii + c_reg * ff;
      c_reg = c;
      float h = tanhfast(c) * oo;
      hOutL[o] = f2bf(h);
    }
    __syncthreads();

    // ---- publish (wave 0 only): 32 coalesced dwordx4 into this WG's
    //      exclusively-owned 512 B, vmcnt ack, then 1 padded-tag store ----
    if (tid < 32) {
      u32x4 v = *(const u32x4*)&hOutL[tid * 8];
      uint16_t* dst = hring + (size_t)((t + 1) & 1) * SLOT +
                      ((size_t)cg * B_ + b0) * 16 + tid * 8;
      store_h16_sys(dst, v);
      asm volatile("s_waitcnt vmcnt(0)" ::: "memory");
      if (tid == 0) {
        __hip_atomic_store(&tags[(bb * GH + cg) * TPAD], t + 1,
                           __ATOMIC_RELAXED, __HIP_MEMORY_SCOPE_SYSTEM);
      }
    }
    // next step's post-poll barrier orders hOutL reuse (wave0 finishes its
    // stores before it can arrive there)
  }
}

// Final projection: out[b,c] = sum_k h[b,k] * Wph[k,c] + bp[c]
// hfin layout: [GH][B_][16] (slot 0 of hring, since T_ is even)
__global__ __launch_bounds__(256) void lstm_proj(
    const uint16_t* __restrict__ hfin,
    const float* __restrict__ Wph,       // [H_][C_]
    const float* __restrict__ bp,        // [C_]
    float* __restrict__ out)             // [B_][C_]
{
  __shared__ float hL[8 * H_];   // 16 KB
  const int tid = threadIdx.x;
  const int b0  = blockIdx.y * 8;
  const int c   = blockIdx.x * 256 + tid;

  {
    int idx = tid * 16;
#pragma unroll
    for (int e = 0; e < 16; ++e) {
      int i = idx + e;
      int rb = i >> 9, k = i & 511;
      hL[i] = bf2f(hfin[((size_t)(k >> 4) * B_ + b0 + rb) * 16 + (k & 15)]);
    }
  }
  __syncthreads();

  if (c < C_) {
    float acc[8] = {0.f, 0.f, 0.f, 0.f, 0.f, 0.f, 0.f, 0.f};
#pragma unroll 8
    for (int k = 0; k < H_; ++k) {
      float w = Wph[(size_t)k * C_ + c];
#pragma unroll
      for (int rb = 0; rb < 8; ++rb) acc[rb] += hL[rb * H_ + k] * w;
    }
    float bias = bp[c];
#pragma unroll
    for (int rb = 0; rb < 8; ++rb) out[(size_t)(b0 + rb) * C_ + c] = acc[rb] + bias;
  }
}

extern "C" void kernel_launch(void* const* d_in, const int* in_sizes, int n_in,
                              void* d_out, int out_size, void* d_ws, size_t ws_size,
                              hipStream_t stream) {
  const float* x   = (const float*)d_in[0];
  const float* Wgx = (const float*)d_in[1];
  const float* Wgh = (const float*)d_in[2];
  const float* bg  = (const float*)d_in[3];
  const float* Wix = (const float*)d_in[4];
  const float* Wih = (const float*)d_in[5];
  const float* bi  = (const float*)d_in[6];
  const float* Wfx = (const float*)d_in[7];
  const float* Wfh = (const float*)d_in[8];
  const float* bf_ = (const float*)d_in[9];
  const float* Wox = (const float*)d_in[10];
  const float* Woh = (const float*)d_in[11];
  const float* bo  = (const float*)d_in[12];
  const float* Wph = (const float*)d_in[13];
  const float* bp  = (const float*)d_in[14];
  float* out = (float*)d_out;

  // ws: hring [2][GH][B_][16] bf16 (256 KB) | tags [GB][GH][TPAD] (32 KB)
  uint16_t* hring = (uint16_t*)d_ws;
  int* tags = (int*)((char*)d_ws + (size_t)2 * GH * B_ * 16 * sizeof(uint16_t));

  hipMemsetAsync(tags, 0, GB * GH * TPAD * sizeof(int), stream);

  lstm_scan<<<dim3(GB * GH), dim3(256), 0, stream>>>(
      x, Wgx, Wgh, bg, Wix, Wih, bi, Wfx, Wfh, bf_, Wox, Woh, bo, hring, tags);

  // h[T] is in slot T%2 == 0
  const uint16_t* hfin = hring;
  lstm_proj<<<dim3(4, 16), dim3(256), 0, stream>>>(hfin, Wph, bp, out);
}

// Round 6
// 2567.492 us; speedup vs baseline: 1.2535x; 1.0874x over previous
//
#include <hip/hip_runtime.h>
#include <stdint.h>

#define B_ 128
#define T_ 1024
#define D_ 256
#define H_ 512
#define C_ 1000
#define GB 8          // batch groups (16 rows each)
#define GH 32         // hidden-column groups (16 units each)
#define ROWS 16       // batch rows per WG
#define UN 16         // hidden units per WG
#define KTOT (H_ + D_)   // 768: fused [h | x] K dimension
#define NCOL 64          // 4 gates * UN
#define LDK (KTOT + 8)   // padded WtL row stride (weight staging, init only)
#define LDX (D_ + 8)     // padded x-tile row stride
#define GST 17           // gpart row stride (floats), +1 pad vs 16
#define TPAD 32          // tag padding: 32 ints = 128 B = 1 line per tag

typedef __bf16 bf16x8 __attribute__((ext_vector_type(8)));
typedef float f32x4 __attribute__((ext_vector_type(4)));
typedef unsigned int u32x4 __attribute__((ext_vector_type(4)));

__device__ __forceinline__ uint16_t f2bf(float f) {
  uint32_t u = __float_as_uint(f);
  u += 0x7FFFu + ((u >> 16) & 1u);   // RNE
  return (uint16_t)(u >> 16);
}
__device__ __forceinline__ float bf2f(uint16_t b) {
  return __uint_as_float(((uint32_t)b) << 16);
}
__device__ __forceinline__ float sigm(float x) { return 1.0f / (1.0f + __expf(-x)); }
__device__ __forceinline__ float tanhfast(float x) { return 2.0f / (1.0f + __expf(-2.0f * x)) - 1.0f; }

// System-scope (sc0 sc1): coherence point = LLC. Safe for any WG placement.
// "=&v" early-clobber so outputs never alias addresses (R1 lesson).
// 4 independent 16B loads + single drain — direct h-fragment load.
__device__ __forceinline__ void load_h4x16_sys(const uint16_t* p0, const uint16_t* p1,
                                               const uint16_t* p2, const uint16_t* p3,
                                               u32x4& a, u32x4& b, u32x4& c, u32x4& d) {
  asm volatile("global_load_dwordx4 %0, %4, off sc0 sc1\n\t"
               "global_load_dwordx4 %1, %5, off sc0 sc1\n\t"
               "global_load_dwordx4 %2, %6, off sc0 sc1\n\t"
               "global_load_dwordx4 %3, %7, off sc0 sc1\n\t"
               "s_waitcnt vmcnt(0)"
               : "=&v"(a), "=&v"(b), "=&v"(c), "=&v"(d)
               : "v"(p0), "v"(p1), "v"(p2), "v"(p3) : "memory");
}
__device__ __forceinline__ void store_h16_sys(uint16_t* p, u32x4 v) {
  asm volatile("global_store_dwordx4 %0, %1, off sc0 sc1"
               :: "v"(p), "v"(v) : "memory");
}

// Persistent scan: 256 WGs (1/CU), 256 threads. WG (bb,cg) owns batch rows
// [bb*16,+16) x hidden units [cg*16,+16) for all 4 gates. Cross-WG comm is
// system-scope via LLC, protocol identical to the proven R0/R5 form.
//
// R6 structural change: WAVE = K-SLICE (not wave = gate).
//   Wave w computes ALL 4 gates over h-K [w*128,+128) and x-K [w*64,+64).
//   Consequences:
//   - each lane's 4 h A-fragments are 16B-contiguous in hring[cg'][b][16]
//     and per-wave coalesced -> h is loaded DIRECTLY from global into MFMA
//     A-registers (proven load_h2x32_sys asm pattern, 4 ptrs). The h LDS
//     staging write, its barrier, and ALL h-side ds_reads (the remaining
//     2.3e8 bank-conflict mass) are deleted. h read exactly once per WG.
//   - B-registers: Bh[4][4]+Bx[4][2] = 96 VGPRs (same count as R5).
//   - cross-gate reduction via gpart[wave][gate][16x16(+pad)] in LDS;
//     pointwise sums the 4 wave partials (16 reads, padded stride 17).
//   - x-part GEMM (h-independent) issues BEFORE the tag poll -> overlaps
//     the wait for producers.
//   Poll/tag/publish unchanged from R0 (R4 proved per-wave polling is a
//   net loss). Slot-reuse invariant preserved: consumer h-loads drain
//   (vmcnt(0) inside asm) before its own publish/tag store.
__global__ __launch_bounds__(256, 1) void lstm_scan(
    const float* __restrict__ x,
    const float* __restrict__ Wgx, const float* __restrict__ Wgh, const float* __restrict__ bg,
    const float* __restrict__ Wix, const float* __restrict__ Wih, const float* __restrict__ bi,
    const float* __restrict__ Wfx, const float* __restrict__ Wfh, const float* __restrict__ bf_,
    const float* __restrict__ Wox, const float* __restrict__ Woh, const float* __restrict__ bo,
    uint16_t* __restrict__ hring,   // [2][GH][B_][16] bf16
    int* __restrict__ tags)         // [GB][GH][TPAD], zeroed before launch
{
  __shared__ __align__(16) uint16_t WtL[NCOL * LDK];   // Bt[n][k] bf16 (init only)
  __shared__ __align__(16) uint16_t ALx[ROWS * LDX];   // x[t] tile bf16
  __shared__ float gpart[4][4][16 * GST];              // [wave][gate][row*17+col]
  __shared__ __align__(16) uint16_t hOutL[ROWS * UN];  // this WG's h slice

  const int tid = threadIdx.x;
  const int wg  = blockIdx.x;
  const int bb  = wg & 7;
  const int cg  = wg >> 3;
  const int b0  = bb * ROWS;
  const int u0  = cg * UN;

  const float* Whs[4] = {Wgh, Wih, Wfh, Woh};
  const float* Wxs[4] = {Wgx, Wix, Wfx, Wox};

  // ---- load weight slice into LDS (transposed: Wt[n][k]) ----
  {
    const int n    = tid & 63;
    const int kk   = tid >> 6;        // 0..3
    const int gate = n >> 4;
    const int j    = u0 + (n & 15);
    const float* WhP = Whs[gate];
    const float* WxP = Wxs[gate];
    for (int k4 = 0; k4 < KTOT; k4 += 4) {
      int k = k4 + kk;
      float w = (k < H_) ? WhP[(size_t)k * H_ + j] : WxP[(size_t)(k - H_) * H_ + j];
      WtL[n * LDK + k] = f2bf(w);
    }
  }

  const int sr = tid >> 4;   // x staging / pointwise row 0..15
  const int sj = tid & 15;   // x staging chunk / pointwise unit 0..15
  const int rr = sr;
  const int uu = sj;

  // thread-pinned state in registers
  float c_reg = 0.0f;
  const float bgr = bg[u0 + uu];
  const float bir = bi[u0 + uu];
  const float bfr = bf_[u0 + uu];
  const float bor = bo[u0 + uu];

  const int lane = tid & 63;
  const int wv   = tid >> 6;          // wave = K-slice
  const int l15  = lane & 15;
  const int q    = lane >> 4;
  const uint16_t* AxBase = &ALx[l15 * LDX + q * 8];
  const int* myTag = &tags[(bb * GH + (lane & 31)) * TPAD];

  // h-fragment byte offsets within a slot (constant per lane):
  // frag j covers k = wv*128 + j*32 + q*8  ->  block cg' = k/16, elem k%16
  uint32_t vo0, vo1, vo2, vo3;
  {
    const int base_cgp = wv * 8 + (q >> 1);
    const int e = (q & 1) * 8;
    vo0 = (uint32_t)((((base_cgp + 0) * B_ + b0 + l15) * 16 + e) * 2);
    vo1 = (uint32_t)((((base_cgp + 2) * B_ + b0 + l15) * 16 + e) * 2);
    vo2 = (uint32_t)((((base_cgp + 4) * B_ + b0 + l15) * 16 + e) * 2);
    vo3 = (uint32_t)((((base_cgp + 6) * B_ + b0 + l15) * 16 + e) * 2);
  }

  // slot stride in shorts for hring[slot][cg][b][16]
  const size_t SLOT = (size_t)GH * B_ * 16;

  // ---- prologue: load x[0] into registers ----
  float4 xr0, xr1, xr2, xr3;
  {
    const float* xsrc = x + ((size_t)(b0 + sr) * T_ + 0) * D_ + sj * 16;
    xr0 = ((const float4*)xsrc)[0];
    xr1 = ((const float4*)xsrc)[1];
    xr2 = ((const float4*)xsrc)[2];
    xr3 = ((const float4*)xsrc)[3];
  }

  __syncthreads();   // WtL complete

  // ---- preload B fragments for this wave's K-slice, all 4 gates ----
  // Bh[g][j]: k = wv*128 + j*32 + q*8 ; Bx[g][jx]: k = H_ + wv*64 + jx*32 + q*8
  bf16x8 Bh[4][4];
  bf16x8 Bx[4][2];
#pragma unroll
  for (int g = 0; g < 4; ++g) {
    const uint16_t* wrow = &WtL[(g * UN + l15) * LDK + q * 8];
#pragma unroll
    for (int j = 0; j < 4; ++j)
      Bh[g][j] = *(const bf16x8*)(wrow + wv * 128 + j * 32);
#pragma unroll
    for (int jx = 0; jx < 2; ++jx)
      Bx[g][jx] = *(const bf16x8*)(wrow + H_ + wv * 64 + jx * 32);
  }

  for (int t = 0; t < T_; ++t) {
    // ---- convert prefetched x[t] -> LDS x tile ----
    {
      uint4 o0, o1;
      o0.x = f2bf(xr0.x) | ((uint32_t)f2bf(xr0.y) << 16);
      o0.y = f2bf(xr0.z) | ((uint32_t)f2bf(xr0.w) << 16);
      o0.z = f2bf(xr1.x) | ((uint32_t)f2bf(xr1.y) << 16);
      o0.w = f2bf(xr1.z) | ((uint32_t)f2bf(xr1.w) << 16);
      o1.x = f2bf(xr2.x) | ((uint32_t)f2bf(xr2.y) << 16);
      o1.y = f2bf(xr2.z) | ((uint32_t)f2bf(xr2.w) << 16);
      o1.z = f2bf(xr3.x) | ((uint32_t)f2bf(xr3.y) << 16);
      o1.w = f2bf(xr3.z) | ((uint32_t)f2bf(xr3.w) << 16);
      uint4* xdst = (uint4*)&ALx[sr * LDX + sj * 16];
      xdst[0] = o0; xdst[1] = o1;
    }
    __syncthreads();   // x tile ready (also orders vs prev-iter gpart reads)

    // ---- x-part GEMM (no h dependency): 2 frags x 4 gates ----
    f32x4 ag0 = {0.f, 0.f, 0.f, 0.f};
    f32x4 ag1 = {0.f, 0.f, 0.f, 0.f};
    f32x4 ag2 = {0.f, 0.f, 0.f, 0.f};
    f32x4 ag3 = {0.f, 0.f, 0.f, 0.f};
#pragma unroll
    for (int jx = 0; jx < 2; ++jx) {
      bf16x8 ax = *(const bf16x8*)(AxBase + wv * 64 + jx * 32);
      ag0 = __builtin_amdgcn_mfma_f32_16x16x32_bf16(ax, Bx[0][jx], ag0, 0, 0, 0);
      ag1 = __builtin_amdgcn_mfma_f32_16x16x32_bf16(ax, Bx[1][jx], ag1, 0, 0, 0);
      ag2 = __builtin_amdgcn_mfma_f32_16x16x32_bf16(ax, Bx[2][jx], ag2, 0, 0, 0);
      ag3 = __builtin_amdgcn_mfma_f32_16x16x32_bf16(ax, Bx[3][jx], ag3, 0, 0, 0);
    }

    // ---- wait for h[t], load fragments direct, h-part GEMM ----
    if (t > 0) {
      if (wv == 0) {
        while (true) {
          int v = __hip_atomic_load(myTag, __ATOMIC_RELAXED,
                                    __HIP_MEMORY_SCOPE_SYSTEM);
          if (__ballot(v < t) == 0ull) break;
        }
      }
      __syncthreads();   // h[t] published & visible at LLC

      const uint16_t* base = hring + (size_t)(t & 1) * SLOT;
      u32x4 h0, h1, h2, h3;
      load_h4x16_sys((const uint16_t*)((const char*)base + vo0),
                     (const uint16_t*)((const char*)base + vo1),
                     (const uint16_t*)((const char*)base + vo2),
                     (const uint16_t*)((const char*)base + vo3),
                     h0, h1, h2, h3);
      bf16x8 ah0 = *(const bf16x8*)&h0;
      bf16x8 ah1 = *(const bf16x8*)&h1;
      bf16x8 ah2 = *(const bf16x8*)&h2;
      bf16x8 ah3 = *(const bf16x8*)&h3;
      // frag j pairs with Bh[g][j] (same k-range), accumulate per gate
      ag0 = __builtin_amdgcn_mfma_f32_16x16x32_bf16(ah0, Bh[0][0], ag0, 0, 0, 0);
      ag1 = __builtin_amdgcn_mfma_f32_16x16x32_bf16(ah0, Bh[1][0], ag1, 0, 0, 0);
      ag2 = __builtin_amdgcn_mfma_f32_16x16x32_bf16(ah0, Bh[2][0], ag2, 0, 0, 0);
      ag3 = __builtin_amdgcn_mfma_f32_16x16x32_bf16(ah0, Bh[3][0], ag3, 0, 0, 0);
      ag0 = __builtin_amdgcn_mfma_f32_16x16x32_bf16(ah1, Bh[0][1], ag0, 0, 0, 0);
      ag1 = __builtin_amdgcn_mfma_f32_16x16x32_bf16(ah1, Bh[1][1], ag1, 0, 0, 0);
      ag2 = __builtin_amdgcn_mfma_f32_16x16x32_bf16(ah1, Bh[2][1], ag2, 0, 0, 0);
      ag3 = __builtin_amdgcn_mfma_f32_16x16x32_bf16(ah1, Bh[3][1], ag3, 0, 0, 0);
      ag0 = __builtin_amdgcn_mfma_f32_16x16x32_bf16(ah2, Bh[0][2], ag0, 0, 0, 0);
      ag1 = __builtin_amdgcn_mfma_f32_16x16x32_bf16(ah2, Bh[1][2], ag1, 0, 0, 0);
      ag2 = __builtin_amdgcn_mfma_f32_16x16x32_bf16(ah2, Bh[2][2], ag2, 0, 0, 0);
      ag3 = __builtin_amdgcn_mfma_f32_16x16x32_bf16(ah2, Bh[3][2], ag3, 0, 0, 0);
      ag0 = __builtin_amdgcn_mfma_f32_16x16x32_bf16(ah3, Bh[0][3], ag0, 0, 0, 0);
      ag1 = __builtin_amdgcn_mfma_f32_16x16x32_bf16(ah3, Bh[1][3], ag1, 0, 0, 0);
      ag2 = __builtin_amdgcn_mfma_f32_16x16x32_bf16(ah3, Bh[2][3], ag2, 0, 0, 0);
      ag3 = __builtin_amdgcn_mfma_f32_16x16x32_bf16(ah3, Bh[3][3], ag3, 0, 0, 0);
    }

    // ---- issue x[t+1] prefetch (after h-asm so its vmcnt doesn't wait) ----
    {
      const int tn = (t + 1 < T_) ? t + 1 : t;
      const float* xsrc = x + ((size_t)(b0 + sr) * T_ + tn) * D_ + sj * 16;
      xr0 = ((const float4*)xsrc)[0];
      xr1 = ((const float4*)xsrc)[1];
      xr2 = ((const float4*)xsrc)[2];
      xr3 = ((const float4*)xsrc)[3];
    }

    // ---- write 4-gate partials: D row = q*4+r, col = l15 ----
#pragma unroll
    for (int r = 0; r < 4; ++r) {
      const int o = (q * 4 + r) * GST + l15;
      gpart[wv][0][o] = ag0[r];
      gpart[wv][1][o] = ag1[r];
      gpart[wv][2][o] = ag2[r];
      gpart[wv][3][o] = ag3[r];
    }
    __syncthreads();

    // ---- pointwise update: thread -> (row rr, unit uu); sum 4 waves ----
    {
      const int o = rr * GST + uu;
      float pg = (gpart[0][0][o] + gpart[1][0][o]) + (gpart[2][0][o] + gpart[3][0][o]) + bgr;
      float pi = (gpart[0][1][o] + gpart[1][1][o]) + (gpart[2][1][o] + gpart[3][1][o]) + bir;
      float pf = (gpart[0][2][o] + gpart[1][2][o]) + (gpart[2][2][o] + gpart[3][2][o]) + bfr;
      float po = (gpart[0][3][o] + gpart[1][3][o]) + (gpart[2][3][o] + gpart[3][3][o]) + bor;
      float g  = tanhfast(pg);
      float ii = sigm(pi);
      float ff = sigm(pf);
      float oo = sigm(po);
      float c  = g * ii + c_reg * ff;
      c_reg = c;
      float h = tanhfast(c) * oo;
      hOutL[rr * UN + uu] = f2bf(h);
    }
    __syncthreads();

    // ---- publish (wave 0 only): 32 coalesced dwordx4 into this WG's
    //      exclusively-owned 512 B, vmcnt ack, then 1 padded-tag store ----
    if (tid < 32) {
      u32x4 v = *(const u32x4*)&hOutL[tid * 8];
      uint16_t* dst = hring + (size_t)((t + 1) & 1) * SLOT +
                      ((size_t)cg * B_ + b0) * 16 + tid * 8;
      store_h16_sys(dst, v);
      asm volatile("s_waitcnt vmcnt(0)" ::: "memory");
      if (tid == 0) {
        __hip_atomic_store(&tags[(bb * GH + cg) * TPAD], t + 1,
                           __ATOMIC_RELAXED, __HIP_MEMORY_SCOPE_SYSTEM);
      }
    }
    // hOutL reuse ordered by the next pointwise barrier chain (wave0
    // finishes its publish reads before it can arrive there)
  }
}

// Final projection: out[b,c] = sum_k h[b,k] * Wph[k,c] + bp[c]
// hfin layout: [GH][B_][16] (slot 0 of hring, since T_ is even)
__global__ __launch_bounds__(256) void lstm_proj(
    const uint16_t* __restrict__ hfin,
    const float* __restrict__ Wph,       // [H_][C_]
    const float* __restrict__ bp,        // [C_]
    float* __restrict__ out)             // [B_][C_]
{
  __shared__ float hL[8 * H_];   // 16 KB
  const int tid = threadIdx.x;
  const int b0  = blockIdx.y * 8;
  const int c   = blockIdx.x * 256 + tid;

  {
    int idx = tid * 16;
#pragma unroll
    for (int e = 0; e < 16; ++e) {
      int i = idx + e;
      int rb = i >> 9, k = i & 511;
      hL[i] = bf2f(hfin[((size_t)(k >> 4) * B_ + b0 + rb) * 16 + (k & 15)]);
    }
  }
  __syncthreads();

  if (c < C_) {
    float acc[8] = {0.f, 0.f, 0.f, 0.f, 0.f, 0.f, 0.f, 0.f};
#pragma unroll 8
    for (int k = 0; k < H_; ++k) {
      float w = Wph[(size_t)k * C_ + c];
#pragma unroll
      for (int rb = 0; rb < 8; ++rb) acc[rb] += hL[rb * H_ + k] * w;
    }
    float bias = bp[c];
#pragma unroll
    for (int rb = 0; rb < 8; ++rb) out[(size_t)(b0 + rb) * C_ + c] = acc[rb] + bias;
  }
}

extern "C" void kernel_launch(void* const* d_in, const int* in_sizes, int n_in,
                              void* d_out, int out_size, void* d_ws, size_t ws_size,
                              hipStream_t stream) {
  const float* x   = (const float*)d_in[0];
  const float* Wgx = (const float*)d_in[1];
  const float* Wgh = (const float*)d_in[2];
  const float* bg  = (const float*)d_in[3];
  const float* Wix = (const float*)d_in[4];
  const float* Wih = (const float*)d_in[5];
  const float* bi  = (const float*)d_in[6];
  const float* Wfx = (const float*)d_in[7];
  const float* Wfh = (const float*)d_in[8];
  const float* bf_ = (const float*)d_in[9];
  const float* Wox = (const float*)d_in[10];
  const float* Woh = (const float*)d_in[11];
  const float* bo  = (const float*)d_in[12];
  const float* Wph = (const float*)d_in[13];
  const float* bp  = (const float*)d_in[14];
  float* out = (float*)d_out;

  // ws: hring [2][GH][B_][16] bf16 (256 KB) | tags [GB][GH][TPAD] (32 KB)
  uint16_t* hring = (uint16_t*)d_ws;
  int* tags = (int*)((char*)d_ws + (size_t)2 * GH * B_ * 16 * sizeof(uint16_t));

  hipMemsetAsync(tags, 0, GB * GH * TPAD * sizeof(int), stream);

  lstm_scan<<<dim3(GB * GH), dim3(256), 0, stream>>>(
      x, Wgx, Wgh, bg, Wix, Wih, bi, Wfx, Wfh, bf_, Wox, Woh, bo, hring, tags);

  // h[T] is in slot T%2 == 0
  const uint16_t* hfin = hring;
  lstm_proj<<<dim3(4, 16), dim3(256), 0, stream>>>(hfin, Wph, bp, out);
}